// Round 1
// baseline (965.359 us; speedup 1.0000x reference)
//
#include <hip/hip_runtime.h>
#include <hip/hip_bf16.h>

// ---------------- degree ----------------
__global__ __launch_bounds__(256) void deg_k(const int* __restrict__ dst, int* __restrict__ cnt, int e) {
    int i = blockIdx.x * 256 + threadIdx.x;
    if (i < e) atomicAdd(&cnt[dst[i]], 1);
}

__global__ __launch_bounds__(256) void dis_k(const int* __restrict__ cnt, float* __restrict__ dis, int n) {
    int i = blockIdx.x * 256 + threadIdx.x;
    if (i < n) dis[i] = rsqrtf((float)cnt[i] + 1.0f);   // +1 = self-loop
}

// ---------------- 3-kernel exclusive scan over cnt -> row_ptr ----------------
__global__ __launch_bounds__(256) void scan1_k(const int* __restrict__ cnt, int* __restrict__ bsum, int n) {
    __shared__ int s[256];
    int i = blockIdx.x * 256 + threadIdx.x;
    int t = threadIdx.x;
    s[t] = (i < n) ? cnt[i] : 0;
    __syncthreads();
    for (int st = 128; st > 0; st >>= 1) {
        if (t < st) s[t] += s[t + st];
        __syncthreads();
    }
    if (t == 0) bsum[blockIdx.x] = s[0];
}

__global__ __launch_bounds__(512) void scan2_k(const int* __restrict__ bsum, int* __restrict__ boff, int nb) {
    __shared__ int s[512];
    int t = threadIdx.x;
    int v = (t < nb) ? bsum[t] : 0;
    s[t] = v;
    __syncthreads();
    for (int st = 1; st < 512; st <<= 1) {
        int add = (t >= st) ? s[t - st] : 0;
        __syncthreads();
        s[t] += add;
        __syncthreads();
    }
    if (t < nb) boff[t] = s[t] - v;   // exclusive
}

__global__ __launch_bounds__(256) void scan3_k(const int* __restrict__ cnt, const int* __restrict__ boff,
                                               int* __restrict__ row_ptr, int n) {
    __shared__ int s[256];
    int i = blockIdx.x * 256 + threadIdx.x;
    int t = threadIdx.x;
    int v = (i < n) ? cnt[i] : 0;
    s[t] = v;
    __syncthreads();
    for (int st = 1; st < 256; st <<= 1) {
        int add = (t >= st) ? s[t - st] : 0;
        __syncthreads();
        s[t] += add;
        __syncthreads();
    }
    int incl = s[t] + boff[blockIdx.x];
    if (i < n) row_ptr[i] = incl - v;
    if (i == n - 1) row_ptr[n] = incl;
}

// ---------------- CSR fill: ed[idx] = {src, norm} ----------------
__global__ __launch_bounds__(256) void fill_k(const int* __restrict__ src, const int* __restrict__ dst,
                                              const int* __restrict__ row_ptr, int* __restrict__ cursor,
                                              const float* __restrict__ dis, int2* __restrict__ ed, int e) {
    int i = blockIdx.x * 256 + threadIdx.x;
    if (i >= e) return;
    int s = src[i], d = dst[i];
    int p = atomicAdd(&cursor[d], 1);
    int2 v;
    v.x = s;
    v.y = __float_as_int(dis[s] * dis[d]);
    ed[row_ptr[d] + p] = v;
}

// ---------------- GEMM: C[n,128] = A[n,128] @ W[128,128] (f32, W in LDS) ----------------
__global__ __launch_bounds__(256) void gemm128_k(const float* __restrict__ A, const float* __restrict__ W,
                                                 float* __restrict__ C, int nrows) {
    __shared__ float Wl[128 * 128];
    __shared__ float Al[16][128];
    int t = threadIdx.x;
    {
        const float4* W4 = (const float4*)W;
        float4* Wl4 = (float4*)Wl;
        for (int i = t; i < 128 * 128 / 4; i += 256) Wl4[i] = W4[i];
    }
    int c  = t & 31;    // cols 4c..4c+3
    int rs = t >> 5;    // rows 2rs, 2rs+1 within tile
    for (int row0 = blockIdx.x * 16; row0 < nrows; row0 += gridDim.x * 16) {
        __syncthreads();   // W ready (first iter) / Al reuse safe (later iters)
        {
            const float4* A4 = (const float4*)(A + (size_t)row0 * 128);
            float4* Al4 = (float4*)&Al[0][0];
            int maxf4 = (nrows - row0 < 16 ? nrows - row0 : 16) * 32;
            for (int i = t; i < 512; i += 256)
                Al4[i] = (i < maxf4) ? A4[i] : make_float4(0.f, 0.f, 0.f, 0.f);
        }
        __syncthreads();
        float4 acc0 = {0.f, 0.f, 0.f, 0.f}, acc1 = {0.f, 0.f, 0.f, 0.f};
        const float* a0p = &Al[2 * rs][0];
        const float* a1p = &Al[2 * rs + 1][0];
#pragma unroll 8
        for (int k = 0; k < 128; k++) {
            float4 w = ((const float4*)(Wl + k * 128))[c];
            float a0 = a0p[k], a1 = a1p[k];
            acc0.x += a0 * w.x; acc0.y += a0 * w.y; acc0.z += a0 * w.z; acc0.w += a0 * w.w;
            acc1.x += a1 * w.x; acc1.y += a1 * w.y; acc1.z += a1 * w.z; acc1.w += a1 * w.w;
        }
        int r0 = row0 + 2 * rs, r1 = r0 + 1;
        if (r0 < nrows) ((float4*)(C + (size_t)r0 * 128))[c] = acc0;
        if (r1 < nrows) ((float4*)(C + (size_t)r1 * 128))[c] = acc1;
    }
}

// ---------------- aggregation: out[n] = relu(b + dis[n]^2*h[n] + sum_e norm*h[src]) ----------------
__global__ __launch_bounds__(256) void agg128_k(const float* __restrict__ h, float* __restrict__ out,
                                                const int* __restrict__ row_ptr, const int2* __restrict__ ed,
                                                const float* __restrict__ dis, const float* __restrict__ bias,
                                                int n) {
    int wid  = (blockIdx.x * 256 + threadIdx.x) >> 6;   // node = global wave id
    int lane = threadIdx.x & 63;
    if (wid >= n) return;
    const float2* hp = (const float2*)h;
    float d  = dis[wid];
    float sl = d * d;
    float2 b  = ((const float2*)bias)[lane];
    float2 hv = hp[(size_t)wid * 64 + lane];
    float2 acc;
    acc.x = b.x + sl * hv.x;
    acc.y = b.y + sl * hv.y;
    int e = row_ptr[wid], e1 = row_ptr[wid + 1];
    for (; e + 4 <= e1; e += 4) {
        int2 d0 = ed[e], d1 = ed[e + 1], d2 = ed[e + 2], d3 = ed[e + 3];
        float2 h0 = hp[(size_t)d0.x * 64 + lane];
        float2 h1 = hp[(size_t)d1.x * 64 + lane];
        float2 h2 = hp[(size_t)d2.x * 64 + lane];
        float2 h3 = hp[(size_t)d3.x * 64 + lane];
        float w0 = __int_as_float(d0.y), w1 = __int_as_float(d1.y);
        float w2 = __int_as_float(d2.y), w3 = __int_as_float(d3.y);
        acc.x += w0 * h0.x + w1 * h1.x + w2 * h2.x + w3 * h3.x;
        acc.y += w0 * h0.y + w1 * h1.y + w2 * h2.y + w3 * h3.y;
    }
    for (; e < e1; e++) {
        int2 dd = ed[e];
        float2 hh = hp[(size_t)dd.x * 64 + lane];
        float ww = __int_as_float(dd.y);
        acc.x += ww * hh.x;
        acc.y += ww * hh.y;
    }
    float2 res;
    res.x = fmaxf(acc.x, 0.f);
    res.y = fmaxf(acc.y, 0.f);
    ((float2*)out)[(size_t)wid * 64 + lane] = res;
}

// ---------------- global mean pool (batch sorted) ----------------
__global__ __launch_bounds__(128) void pool_k(const float* __restrict__ h, const int* __restrict__ batch,
                                              float* __restrict__ pooled, int n) {
    int g = blockIdx.x;
    int j = threadIdx.x;
    int lo = 0, hi = n;
    while (lo < hi) { int mid = (lo + hi) >> 1; if (batch[mid] < g) lo = mid + 1; else hi = mid; }
    int start = lo;
    hi = n;
    while (lo < hi) { int mid = (lo + hi) >> 1; if (batch[mid] < g + 1) lo = mid + 1; else hi = mid; }
    int end = lo;
    float acc = 0.f;
    for (int r = start; r < end; r++) acc += h[(size_t)r * 128 + j];
    float cntf = (float)(end - start);
    pooled[(size_t)g * 128 + j] = acc / fmaxf(cntf, 1.0f);
}

// ---------------- classifier: logits = pooled @ Wc + bc ----------------
__global__ __launch_bounds__(64) void logits_k(const float* __restrict__ pooled, const float* __restrict__ Wc,
                                               const float* __restrict__ bc, float* __restrict__ out, int nc) {
    int g = blockIdx.x;
    int j = threadIdx.x;
    if (j >= nc) return;
    float acc = bc[j];
    const float* p = pooled + (size_t)g * 128;
#pragma unroll 8
    for (int k = 0; k < 128; k++) acc += p[k] * Wc[k * nc + j];
    out[(size_t)g * nc + j] = acc;
}

extern "C" void kernel_launch(void* const* d_in, const int* in_sizes, int n_in,
                              void* d_out, int out_size, void* d_ws, size_t ws_size,
                              hipStream_t stream) {
    const float* x     = (const float*)d_in[0];
    const int*   ei    = (const int*)d_in[1];
    const int*   batch = (const int*)d_in[2];
    const float* W1    = (const float*)d_in[3];
    const float* b1    = (const float*)d_in[4];
    const float* W2    = (const float*)d_in[5];
    const float* b2    = (const float*)d_in[6];
    const float* Wc    = (const float*)d_in[7];
    const float* bc    = (const float*)d_in[8];
    float* out = (float*)d_out;

    const int N = in_sizes[0] / 128;
    const int E = in_sizes[1] / 2;
    const int NC = 10;
    const int G = out_size / (NC + 128);

    const int* src = ei;
    const int* dst = ei + E;

    // workspace carve (256B aligned)
    char* wbase = (char*)d_ws;
    size_t off = 0;
    auto alloc = [&](size_t bytes) -> void* {
        void* p = wbase + off;
        off = (off + bytes + 255) & ~(size_t)255;
        return p;
    };
    int*   cnt     = (int*)alloc((size_t)N * 4);
    int*   cursor  = (int*)alloc((size_t)N * 4);
    float* dis     = (float*)alloc((size_t)N * 4);
    int*   row_ptr = (int*)alloc((size_t)(N + 1) * 4);
    const int NB = (N + 255) / 256;
    int*   bsum    = (int*)alloc((size_t)NB * 4);
    int*   boff    = (int*)alloc((size_t)NB * 4);
    int2*  ed      = (int2*)alloc((size_t)E * 8);
    float* bufT    = (float*)alloc((size_t)N * 128 * 4);
    float* bufH    = (float*)alloc((size_t)N * 128 * 4);

    hipMemsetAsync(cnt, 0, (size_t)N * 4, stream);
    hipMemsetAsync(cursor, 0, (size_t)N * 4, stream);

    deg_k<<<(E + 255) / 256, 256, 0, stream>>>(dst, cnt, E);
    dis_k<<<(N + 255) / 256, 256, 0, stream>>>(cnt, dis, N);
    scan1_k<<<NB, 256, 0, stream>>>(cnt, bsum, N);
    scan2_k<<<1, 512, 0, stream>>>(bsum, boff, NB);
    scan3_k<<<NB, 256, 0, stream>>>(cnt, boff, row_ptr, N);
    fill_k<<<(E + 255) / 256, 256, 0, stream>>>(src, dst, row_ptr, cursor, dis, ed, E);

    gemm128_k<<<2048, 256, 0, stream>>>(x, W1, bufT, N);
    agg128_k<<<(N + 3) / 4, 256, 0, stream>>>(bufT, bufH, row_ptr, ed, dis, b1, N);
    gemm128_k<<<2048, 256, 0, stream>>>(bufH, W2, bufT, N);
    agg128_k<<<(N + 3) / 4, 256, 0, stream>>>(bufT, bufH, row_ptr, ed, dis, b2, N);

    float* pooled = out + (size_t)G * NC;
    pool_k<<<G, 128, 0, stream>>>(bufH, batch, pooled, N);
    logits_k<<<G, 64, 0, stream>>>(pooled, Wc, bc, out, NC);
}

// Round 2
// 803.741 us; speedup vs baseline: 1.2011x; 1.2011x over previous
//
#include <hip/hip_runtime.h>
#include <hip/hip_bf16.h>

__device__ __forceinline__ unsigned short f2bf(float f) {
    unsigned int u = __float_as_uint(f);
    unsigned int r = u + 0x7fffu + ((u >> 16) & 1u);
    return (unsigned short)(r >> 16);
}
__device__ __forceinline__ float bf2f(unsigned short b) {
    return __uint_as_float(((unsigned int)b) << 16);
}

// ---------------- cast f32 -> bf16 ----------------
__global__ __launch_bounds__(256) void cast_bf_k(const float* __restrict__ x, unsigned short* __restrict__ o, int n4) {
    int i = blockIdx.x * 256 + threadIdx.x;
    if (i < n4) {
        float4 v = ((const float4*)x)[i];
        ushort4 r;
        r.x = f2bf(v.x); r.y = f2bf(v.y); r.z = f2bf(v.z); r.w = f2bf(v.w);
        ((ushort4*)o)[i] = r;
    }
}

// ---------------- degree ----------------
__global__ __launch_bounds__(256) void deg_k(const int* __restrict__ dst, int* __restrict__ cnt, int e) {
    int i = blockIdx.x * 256 + threadIdx.x;
    if (i < e) atomicAdd(&cnt[dst[i]], 1);
}

__global__ __launch_bounds__(256) void dis_k(const int* __restrict__ cnt, float* __restrict__ dis, int n) {
    int i = blockIdx.x * 256 + threadIdx.x;
    if (i < n) dis[i] = rsqrtf((float)cnt[i] + 1.0f);   // +1 = self-loop
}

// ---------------- 3-kernel exclusive scan over cnt -> row_ptr ----------------
__global__ __launch_bounds__(256) void scan1_k(const int* __restrict__ cnt, int* __restrict__ bsum, int n) {
    __shared__ int s[256];
    int i = blockIdx.x * 256 + threadIdx.x;
    int t = threadIdx.x;
    s[t] = (i < n) ? cnt[i] : 0;
    __syncthreads();
    for (int st = 128; st > 0; st >>= 1) {
        if (t < st) s[t] += s[t + st];
        __syncthreads();
    }
    if (t == 0) bsum[blockIdx.x] = s[0];
}

__global__ __launch_bounds__(512) void scan2_k(const int* __restrict__ bsum, int* __restrict__ boff, int nb) {
    __shared__ int s[512];
    int t = threadIdx.x;
    int v = (t < nb) ? bsum[t] : 0;
    s[t] = v;
    __syncthreads();
    for (int st = 1; st < 512; st <<= 1) {
        int add = (t >= st) ? s[t - st] : 0;
        __syncthreads();
        s[t] += add;
        __syncthreads();
    }
    if (t < nb) boff[t] = s[t] - v;   // exclusive
}

__global__ __launch_bounds__(256) void scan3_k(const int* __restrict__ cnt, const int* __restrict__ boff,
                                               int* __restrict__ row_ptr, int n) {
    __shared__ int s[256];
    int i = blockIdx.x * 256 + threadIdx.x;
    int t = threadIdx.x;
    int v = (i < n) ? cnt[i] : 0;
    s[t] = v;
    __syncthreads();
    for (int st = 1; st < 256; st <<= 1) {
        int add = (t >= st) ? s[t - st] : 0;
        __syncthreads();
        s[t] += add;
        __syncthreads();
    }
    int incl = s[t] + boff[blockIdx.x];
    if (i < n) row_ptr[i] = incl - v;
    if (i == n - 1) row_ptr[n] = incl;
}

// ---------------- CSR fill: ed[idx] = {src, norm} ----------------
__global__ __launch_bounds__(256) void fill_k(const int* __restrict__ src, const int* __restrict__ dst,
                                              const int* __restrict__ row_ptr, int* __restrict__ cursor,
                                              const float* __restrict__ dis, int2* __restrict__ ed, int e) {
    int i = blockIdx.x * 256 + threadIdx.x;
    if (i >= e) return;
    int s = src[i], d = dst[i];
    int p = atomicAdd(&cursor[d], 1);
    int2 v;
    v.x = s;
    v.y = __float_as_int(dis[s] * dis[d]);
    ed[row_ptr[d] + p] = v;
}

// ---------------- GEMM: C[n,128] = A[n,128] @ W[128,128]; A,C bf16, f32 accum ----------------
__global__ __launch_bounds__(256) void gemm128bf_k(const unsigned short* __restrict__ A, const float* __restrict__ W,
                                                   unsigned short* __restrict__ C, int nrows) {
    __shared__ unsigned short Wl[128 * 128];   // 32 KB bf16
    __shared__ unsigned short Al[16][128];     // 4 KB
    int t = threadIdx.x;
    {
        const float4* W4 = (const float4*)W;
        ushort4* Wl4 = (ushort4*)Wl;
        for (int i = t; i < 128 * 128 / 4; i += 256) {
            float4 w = W4[i];
            ushort4 o;
            o.x = f2bf(w.x); o.y = f2bf(w.y); o.z = f2bf(w.z); o.w = f2bf(w.w);
            Wl4[i] = o;
        }
    }
    int c  = t & 31;    // cols 4c..4c+3
    int rs = t >> 5;    // rows 2rs, 2rs+1 within tile
    for (int row0 = blockIdx.x * 16; row0 < nrows; row0 += gridDim.x * 16) {
        __syncthreads();   // W ready (first iter) / Al reuse safe (later iters)
        {
            const uint4* A4 = (const uint4*)(A + (size_t)row0 * 128);
            uint4* Al4 = (uint4*)&Al[0][0];
            int maxv = (nrows - row0 < 16 ? nrows - row0 : 16) * 16;   // uint4 per row = 16
            Al4[t] = (t < maxv) ? A4[t] : make_uint4(0u, 0u, 0u, 0u);
        }
        __syncthreads();
        float4 acc0 = {0.f, 0.f, 0.f, 0.f}, acc1 = {0.f, 0.f, 0.f, 0.f};
        const unsigned short* a0p = &Al[2 * rs][0];
        const unsigned short* a1p = &Al[2 * rs + 1][0];
#pragma unroll 8
        for (int k = 0; k < 128; k++) {
            uint2 wp = ((const uint2*)Wl)[k * 32 + c];
            float w0 = __uint_as_float(wp.x << 16);
            float w1 = __uint_as_float(wp.x & 0xffff0000u);
            float w2 = __uint_as_float(wp.y << 16);
            float w3 = __uint_as_float(wp.y & 0xffff0000u);
            float a0 = bf2f(a0p[k]);
            float a1 = bf2f(a1p[k]);
            acc0.x += a0 * w0; acc0.y += a0 * w1; acc0.z += a0 * w2; acc0.w += a0 * w3;
            acc1.x += a1 * w0; acc1.y += a1 * w1; acc1.z += a1 * w2; acc1.w += a1 * w3;
        }
        int r0 = row0 + 2 * rs, r1 = r0 + 1;
        if (r0 < nrows) {
            ushort4 o; o.x = f2bf(acc0.x); o.y = f2bf(acc0.y); o.z = f2bf(acc0.z); o.w = f2bf(acc0.w);
            ((ushort4*)(C + (size_t)r0 * 128))[c] = o;
        }
        if (r1 < nrows) {
            ushort4 o; o.x = f2bf(acc1.x); o.y = f2bf(acc1.y); o.z = f2bf(acc1.z); o.w = f2bf(acc1.w);
            ((ushort4*)(C + (size_t)r1 * 128))[c] = o;
        }
    }
}

// ---------------- aggregation: out[n] = relu(b + dis[n]^2*h[n] + sum_e norm*h[src]); h bf16 ----------------
__global__ __launch_bounds__(256) void agg128bf_k(const unsigned short* __restrict__ h, unsigned short* __restrict__ out,
                                                  const int* __restrict__ row_ptr, const int2* __restrict__ ed,
                                                  const float* __restrict__ dis, const float* __restrict__ bias,
                                                  int n) {
    int wid  = (blockIdx.x * 256 + threadIdx.x) >> 6;   // node = global wave id
    int lane = threadIdx.x & 63;
    if (wid >= n) return;
    const unsigned int* hp = (const unsigned int*)h;    // bf16x2, row stride 64
    float d  = dis[wid];
    float sl = d * d;
    float2 b = ((const float2*)bias)[lane];
    unsigned int hv = hp[(size_t)wid * 64 + lane];
    float accx = b.x + sl * __uint_as_float(hv << 16);
    float accy = b.y + sl * __uint_as_float(hv & 0xffff0000u);
    int e = row_ptr[wid], e1 = row_ptr[wid + 1];
    for (; e + 8 <= e1; e += 8) {
        int2 d0 = ed[e],     d1 = ed[e + 1], d2 = ed[e + 2], d3 = ed[e + 3];
        int2 d4 = ed[e + 4], d5 = ed[e + 5], d6 = ed[e + 6], d7 = ed[e + 7];
        unsigned int h0 = hp[(size_t)d0.x * 64 + lane];
        unsigned int h1 = hp[(size_t)d1.x * 64 + lane];
        unsigned int h2 = hp[(size_t)d2.x * 64 + lane];
        unsigned int h3 = hp[(size_t)d3.x * 64 + lane];
        unsigned int h4 = hp[(size_t)d4.x * 64 + lane];
        unsigned int h5 = hp[(size_t)d5.x * 64 + lane];
        unsigned int h6 = hp[(size_t)d6.x * 64 + lane];
        unsigned int h7 = hp[(size_t)d7.x * 64 + lane];
        float w0 = __int_as_float(d0.y), w1 = __int_as_float(d1.y);
        float w2 = __int_as_float(d2.y), w3 = __int_as_float(d3.y);
        float w4 = __int_as_float(d4.y), w5 = __int_as_float(d5.y);
        float w6 = __int_as_float(d6.y), w7 = __int_as_float(d7.y);
        accx += w0 * __uint_as_float(h0 << 16) + w1 * __uint_as_float(h1 << 16)
              + w2 * __uint_as_float(h2 << 16) + w3 * __uint_as_float(h3 << 16)
              + w4 * __uint_as_float(h4 << 16) + w5 * __uint_as_float(h5 << 16)
              + w6 * __uint_as_float(h6 << 16) + w7 * __uint_as_float(h7 << 16);
        accy += w0 * __uint_as_float(h0 & 0xffff0000u) + w1 * __uint_as_float(h1 & 0xffff0000u)
              + w2 * __uint_as_float(h2 & 0xffff0000u) + w3 * __uint_as_float(h3 & 0xffff0000u)
              + w4 * __uint_as_float(h4 & 0xffff0000u) + w5 * __uint_as_float(h5 & 0xffff0000u)
              + w6 * __uint_as_float(h6 & 0xffff0000u) + w7 * __uint_as_float(h7 & 0xffff0000u);
    }
    for (; e < e1; e++) {
        int2 dd = ed[e];
        unsigned int hh = hp[(size_t)dd.x * 64 + lane];
        float ww = __int_as_float(dd.y);
        accx += ww * __uint_as_float(hh << 16);
        accy += ww * __uint_as_float(hh & 0xffff0000u);
    }
    unsigned int res = ((unsigned int)f2bf(fmaxf(accy, 0.f)) << 16) | (unsigned int)f2bf(fmaxf(accx, 0.f));
    ((unsigned int*)out)[(size_t)wid * 64 + lane] = res;
}

// ---------------- global mean pool (batch sorted), h bf16 -> pooled f32 ----------------
__global__ __launch_bounds__(128) void pool_k(const unsigned short* __restrict__ h, const int* __restrict__ batch,
                                              float* __restrict__ pooled, int n) {
    int g = blockIdx.x;
    int j = threadIdx.x;
    int lo = 0, hi = n;
    while (lo < hi) { int mid = (lo + hi) >> 1; if (batch[mid] < g) lo = mid + 1; else hi = mid; }
    int start = lo;
    hi = n;
    while (lo < hi) { int mid = (lo + hi) >> 1; if (batch[mid] < g + 1) lo = mid + 1; else hi = mid; }
    int end = lo;
    float acc = 0.f;
    for (int r = start; r < end; r++) acc += bf2f(h[(size_t)r * 128 + j]);
    float cntf = (float)(end - start);
    pooled[(size_t)g * 128 + j] = acc / fmaxf(cntf, 1.0f);
}

// ---------------- classifier: logits = pooled @ Wc + bc ----------------
__global__ __launch_bounds__(64) void logits_k(const float* __restrict__ pooled, const float* __restrict__ Wc,
                                               const float* __restrict__ bc, float* __restrict__ out, int nc) {
    int g = blockIdx.x;
    int j = threadIdx.x;
    if (j >= nc) return;
    float acc = bc[j];
    const float* p = pooled + (size_t)g * 128;
#pragma unroll 8
    for (int k = 0; k < 128; k++) acc += p[k] * Wc[k * nc + j];
    out[(size_t)g * nc + j] = acc;
}

extern "C" void kernel_launch(void* const* d_in, const int* in_sizes, int n_in,
                              void* d_out, int out_size, void* d_ws, size_t ws_size,
                              hipStream_t stream) {
    const float* x     = (const float*)d_in[0];
    const int*   ei    = (const int*)d_in[1];
    const int*   batch = (const int*)d_in[2];
    const float* W1    = (const float*)d_in[3];
    const float* b1    = (const float*)d_in[4];
    const float* W2    = (const float*)d_in[5];
    const float* b2    = (const float*)d_in[6];
    const float* Wc    = (const float*)d_in[7];
    const float* bc    = (const float*)d_in[8];
    float* out = (float*)d_out;

    const int N = in_sizes[0] / 128;
    const int E = in_sizes[1] / 2;
    const int NC = 10;
    const int G = out_size / (NC + 128);

    const int* src = ei;
    const int* dst = ei + E;

    // workspace carve (256B aligned)
    char* wbase = (char*)d_ws;
    size_t off = 0;
    auto alloc = [&](size_t bytes) -> void* {
        void* p = wbase + off;
        off = (off + bytes + 255) & ~(size_t)255;
        return p;
    };
    int*   cnt     = (int*)alloc((size_t)N * 4);
    int*   cursor  = (int*)alloc((size_t)N * 4);
    float* dis     = (float*)alloc((size_t)N * 4);
    int*   row_ptr = (int*)alloc((size_t)(N + 1) * 4);
    const int NB = (N + 255) / 256;
    int*   bsum    = (int*)alloc((size_t)NB * 4);
    int*   boff    = (int*)alloc((size_t)NB * 4);
    int2*  ed      = (int2*)alloc((size_t)E * 8);
    unsigned short* bufX = (unsigned short*)alloc((size_t)N * 128 * 2);
    unsigned short* bufT = (unsigned short*)alloc((size_t)N * 128 * 2);
    unsigned short* bufH = (unsigned short*)alloc((size_t)N * 128 * 2);

    hipMemsetAsync(cnt, 0, (size_t)N * 4, stream);
    hipMemsetAsync(cursor, 0, (size_t)N * 4, stream);

    cast_bf_k<<<(N * 128 / 4 + 255) / 256, 256, 0, stream>>>(x, bufX, N * 128 / 4);
    deg_k<<<(E + 255) / 256, 256, 0, stream>>>(dst, cnt, E);
    dis_k<<<(N + 255) / 256, 256, 0, stream>>>(cnt, dis, N);
    scan1_k<<<NB, 256, 0, stream>>>(cnt, bsum, N);
    scan2_k<<<1, 512, 0, stream>>>(bsum, boff, NB);
    scan3_k<<<NB, 256, 0, stream>>>(cnt, boff, row_ptr, N);
    fill_k<<<(E + 255) / 256, 256, 0, stream>>>(src, dst, row_ptr, cursor, dis, ed, E);

    gemm128bf_k<<<3125, 256, 0, stream>>>(bufX, W1, bufT, N);
    agg128bf_k<<<(N + 3) / 4, 256, 0, stream>>>(bufT, bufH, row_ptr, ed, dis, b1, N);
    gemm128bf_k<<<3125, 256, 0, stream>>>(bufH, W2, bufT, N);
    agg128bf_k<<<(N + 3) / 4, 256, 0, stream>>>(bufT, bufH, row_ptr, ed, dis, b2, N);

    float* pooled = out + (size_t)G * NC;
    pool_k<<<G, 128, 0, stream>>>(bufH, batch, pooled, N);
    logits_k<<<G, 64, 0, stream>>>(pooled, Wc, bc, out, NC);
}

// Round 3
// 431.816 us; speedup vs baseline: 2.2356x; 1.8613x over previous
//
#include <hip/hip_runtime.h>
#include <hip/hip_bf16.h>

typedef short bf16x8 __attribute__((ext_vector_type(8)));
typedef float f32x4 __attribute__((ext_vector_type(4)));
typedef unsigned int u32x4 __attribute__((ext_vector_type(4)));

__device__ __forceinline__ unsigned short f2bf(float f) {
    unsigned int u = __float_as_uint(f);
    unsigned int r = u + 0x7fffu + ((u >> 16) & 1u);
    return (unsigned short)(r >> 16);
}
__device__ __forceinline__ float bf2f(unsigned short b) {
    return __uint_as_float(((unsigned int)b) << 16);
}

// ---------------- cast f32 -> bf16 ----------------
__global__ __launch_bounds__(256) void cast_bf_k(const float* __restrict__ x, unsigned short* __restrict__ o, int n4) {
    int i = blockIdx.x * 256 + threadIdx.x;
    if (i < n4) {
        float4 v = ((const float4*)x)[i];
        ushort4 r;
        r.x = f2bf(v.x); r.y = f2bf(v.y); r.z = f2bf(v.z); r.w = f2bf(v.w);
        ((ushort4*)o)[i] = r;
    }
}

// ---------------- pass 1: per-block bucket histogram (bucket = dst>>8) ----------------
__global__ __launch_bounds__(256) void hist_k(const int* __restrict__ dst, int* __restrict__ hist,
                                              int e, int nbuk, int nblk, int eb) {
    __shared__ int lh[512];
    int blk = blockIdx.x, t = threadIdx.x;
    for (int j = t; j < nbuk; j += 256) lh[j] = 0;
    __syncthreads();
    int e0 = blk * eb, e1 = min(e, e0 + eb);
    for (int i = e0 + t; i < e1; i += 256) atomicAdd(&lh[dst[i] >> 8], 1);
    __syncthreads();
    for (int j = t; j < nbuk; j += 256) hist[(size_t)j * nblk + blk] = lh[j];
}

// ---------------- pass 2a: per-bucket exclusive scan over blocks; bucket totals ----------------
__global__ __launch_bounds__(256) void scanA_k(int* __restrict__ hist, int* __restrict__ btot, int nbuk, int nblk) {
    int w = (blockIdx.x * 256 + threadIdx.x) >> 6;
    int lane = threadIdx.x & 63;
    if (w >= nbuk) return;
    size_t base = (size_t)w * nblk;
    int run = 0;
    for (int c = 0; c < nblk; c += 64) {
        int i = c + lane;
        int v = (i < nblk) ? hist[base + i] : 0;
        int orig = v;
        for (int d = 1; d < 64; d <<= 1) { int u = __shfl_up(v, d); if (lane >= d) v += u; }
        if (i < nblk) hist[base + i] = run + v - orig;   // exclusive within bucket
        run += __shfl(v, 63);
    }
    if (lane == 0) btot[w] = run;
}

// ---------------- pass 2b: scan bucket totals -> bucket bases ----------------
__global__ __launch_bounds__(512) void scanB_k(const int* __restrict__ btot, int* __restrict__ bbase, int nbuk) {
    __shared__ int s[512];
    int t = threadIdx.x;
    int v = (t < nbuk) ? btot[t] : 0;
    s[t] = v;
    __syncthreads();
    for (int st = 1; st < 512; st <<= 1) {
        int add = (t >= st) ? s[t - st] : 0;
        __syncthreads();
        s[t] += add;
        __syncthreads();
    }
    if (t < nbuk) bbase[t] = s[t] - v;
    if (t == nbuk - 1) bbase[nbuk] = s[t];
}

// ---------------- pass 3: coarse scatter into bucket regions (packed dstlocal|src) ----------------
__global__ __launch_bounds__(256) void scatter_k(const int* __restrict__ src, const int* __restrict__ dst,
                                                 const int* __restrict__ hist, const int* __restrict__ bbase,
                                                 unsigned int* __restrict__ coarse, int e, int nbuk, int nblk, int eb) {
    __shared__ int cur[512];
    int blk = blockIdx.x, t = threadIdx.x;
    for (int j = t; j < nbuk; j += 256) cur[j] = bbase[j] + hist[(size_t)j * nblk + blk];
    __syncthreads();
    int e0 = blk * eb, e1 = min(e, e0 + eb);
    for (int i = e0 + t; i < e1; i += 256) {
        int s = src[i], d = dst[i];
        int bk = d >> 8;
        int p = atomicAdd(&cur[bk], 1);
        coarse[p] = ((unsigned int)(d & 255) << 24) | (unsigned int)s;
    }
}

// ---------------- pass 4: per-bucket fine sort -> cnt, row_ptr, col ----------------
__global__ __launch_bounds__(256) void bucket_k(const unsigned int* __restrict__ coarse, const int* __restrict__ bbase,
                                                int* __restrict__ cnt, int* __restrict__ row_ptr, int* __restrict__ col,
                                                int n, int nbuk, int e) {
    __shared__ int h[256];
    __shared__ int s[256];
    __shared__ int cur[256];
    int b = blockIdx.x, t = threadIdx.x;
    int e0 = bbase[b], e1 = bbase[b + 1];
    h[t] = 0;
    __syncthreads();
    for (int i = e0 + t; i < e1; i += 256) atomicAdd(&h[coarse[i] >> 24], 1);
    __syncthreads();
    int v = h[t];
    s[t] = v;
    __syncthreads();
    for (int st = 1; st < 256; st <<= 1) {
        int add = (t >= st) ? s[t - st] : 0;
        __syncthreads();
        s[t] += add;
        __syncthreads();
    }
    int excl = s[t] - v;
    int node = b * 256 + t;
    if (node < n) { cnt[node] = v; row_ptr[node] = e0 + excl; }
    cur[t] = e0 + excl;
    __syncthreads();
    for (int i = e0 + t; i < e1; i += 256) {
        unsigned int pk = coarse[i];
        int p = atomicAdd(&cur[pk >> 24], 1);
        col[p] = (int)(pk & 0x00FFFFFFu);
    }
    if (b == nbuk - 1 && t == 0) row_ptr[n] = e;
}

// ---------------- dis = rsqrt(deg+1) ----------------
__global__ __launch_bounds__(256) void dis_k(const int* __restrict__ cnt, float* __restrict__ dis, int n) {
    int i = blockIdx.x * 256 + threadIdx.x;
    if (i < n) dis[i] = rsqrtf((float)cnt[i] + 1.0f);
}

// ---------------- MFMA GEMM: C[r] = dis[r] * (A[r] @ W), A/C bf16, W f32 staged as W^T bf16 ----------------
__global__ __launch_bounds__(256) void gemm_mfma_k(const unsigned short* __restrict__ A, const float* __restrict__ W,
                                                   const float* __restrict__ dis, unsigned short* __restrict__ C,
                                                   int nrows) {
    __shared__ unsigned short WT[128 * 136];   // W^T[n][k], pad ld=136 to dodge bank conflicts
    int t = threadIdx.x;
    for (int i = t; i < 16384; i += 256) {
        int k = i >> 7, nn = i & 127;
        WT[nn * 136 + k] = f2bf(W[i]);
    }
    __syncthreads();
    int wave = t >> 6, lane = t & 63;
    int lm = lane & 15, lg = lane >> 4;      // lg in 0..3
    for (int m0 = blockIdx.x * 64; m0 < nrows; m0 += gridDim.x * 64) {
        int R = m0 + wave * 16;
        int arow = R + lm;
        if (arow >= nrows) arow = nrows - 1;
        const u32x4* ap = (const u32x4*)(A + (size_t)arow * 128);
        f32x4 acc[8];
#pragma unroll
        for (int q = 0; q < 8; q++) acc[q] = (f32x4){0.f, 0.f, 0.f, 0.f};
#pragma unroll
        for (int kk = 0; kk < 4; kk++) {
            bf16x8 af = __builtin_bit_cast(bf16x8, ap[kk * 4 + lg]);   // A[m=lm][k=kk*32+lg*8 ..+7]
#pragma unroll
            for (int q = 0; q < 8; q++) {
                const u32x4* bp = (const u32x4*)(WT + (q * 16 + lm) * 136 + kk * 32 + lg * 8);
                bf16x8 bfr = __builtin_bit_cast(bf16x8, *bp);          // B[k][n=q*16+lm]
                acc[q] = __builtin_amdgcn_mfma_f32_16x16x32_bf16(af, bfr, acc[q], 0, 0, 0);
            }
        }
        float dsc[4];
#pragma unroll
        for (int i2 = 0; i2 < 4; i2++) {
            int r = R + lg * 4 + i2;
            dsc[i2] = (r < nrows) ? dis[r] : 0.f;
        }
#pragma unroll
        for (int i2 = 0; i2 < 4; i2++) {
            int r = R + lg * 4 + i2;
            if (r < nrows) {
                unsigned short* cp = C + (size_t)r * 128 + lm;
#pragma unroll
                for (int q = 0; q < 8; q++) cp[q * 16] = f2bf(acc[q][i2] * dsc[i2]);
            }
        }
    }
}

// ---------------- aggregation: out[n] = relu(b + dis[n]*(h'[n] + sum h'[col[e]])) ----------------
__global__ __launch_bounds__(256) void agg_k(const unsigned short* __restrict__ h, unsigned short* __restrict__ out,
                                             const int* __restrict__ row_ptr, const int* __restrict__ col,
                                             const float* __restrict__ dis, const float* __restrict__ bias, int n) {
    int wid  = (blockIdx.x * 256 + threadIdx.x) >> 6;
    int lane = threadIdx.x & 63;
    if (wid >= n) return;
    const unsigned int* hp = (const unsigned int*)h;    // bf16x2, row stride 64
    unsigned int hv = hp[(size_t)wid * 64 + lane];
    float accx = __uint_as_float(hv << 16);
    float accy = __uint_as_float(hv & 0xffff0000u);
    int e = row_ptr[wid], e1 = row_ptr[wid + 1];
    for (; e + 8 <= e1; e += 8) {
        int c0 = col[e],     c1 = col[e + 1], c2 = col[e + 2], c3 = col[e + 3];
        int c4 = col[e + 4], c5 = col[e + 5], c6 = col[e + 6], c7 = col[e + 7];
        unsigned int h0 = hp[(size_t)c0 * 64 + lane];
        unsigned int h1 = hp[(size_t)c1 * 64 + lane];
        unsigned int h2 = hp[(size_t)c2 * 64 + lane];
        unsigned int h3 = hp[(size_t)c3 * 64 + lane];
        unsigned int h4 = hp[(size_t)c4 * 64 + lane];
        unsigned int h5 = hp[(size_t)c5 * 64 + lane];
        unsigned int h6 = hp[(size_t)c6 * 64 + lane];
        unsigned int h7 = hp[(size_t)c7 * 64 + lane];
        accx += __uint_as_float(h0 << 16) + __uint_as_float(h1 << 16)
              + __uint_as_float(h2 << 16) + __uint_as_float(h3 << 16)
              + __uint_as_float(h4 << 16) + __uint_as_float(h5 << 16)
              + __uint_as_float(h6 << 16) + __uint_as_float(h7 << 16);
        accy += __uint_as_float(h0 & 0xffff0000u) + __uint_as_float(h1 & 0xffff0000u)
              + __uint_as_float(h2 & 0xffff0000u) + __uint_as_float(h3 & 0xffff0000u)
              + __uint_as_float(h4 & 0xffff0000u) + __uint_as_float(h5 & 0xffff0000u)
              + __uint_as_float(h6 & 0xffff0000u) + __uint_as_float(h7 & 0xffff0000u);
    }
    for (; e < e1; e++) {
        unsigned int hh = hp[(size_t)col[e] * 64 + lane];
        accx += __uint_as_float(hh << 16);
        accy += __uint_as_float(hh & 0xffff0000u);
    }
    float d = dis[wid];
    float2 b = ((const float2*)bias)[lane];
    unsigned int res = ((unsigned int)f2bf(fmaxf(b.y + d * accy, 0.f)) << 16)
                     |  (unsigned int)f2bf(fmaxf(b.x + d * accx, 0.f));
    ((unsigned int*)out)[(size_t)wid * 64 + lane] = res;
}

// ---------------- global mean pool (batch sorted), h bf16 -> pooled f32 ----------------
__global__ __launch_bounds__(128) void pool_k(const unsigned short* __restrict__ h, const int* __restrict__ batch,
                                              float* __restrict__ pooled, int n) {
    int g = blockIdx.x;
    int j = threadIdx.x;
    int lo = 0, hi = n;
    while (lo < hi) { int mid = (lo + hi) >> 1; if (batch[mid] < g) lo = mid + 1; else hi = mid; }
    int start = lo;
    hi = n;
    while (lo < hi) { int mid = (lo + hi) >> 1; if (batch[mid] < g + 1) lo = mid + 1; else hi = mid; }
    int end = lo;
    float acc = 0.f;
    for (int r = start; r < end; r++) acc += bf2f(h[(size_t)r * 128 + j]);
    float cntf = (float)(end - start);
    pooled[(size_t)g * 128 + j] = acc / fmaxf(cntf, 1.0f);
}

// ---------------- classifier ----------------
__global__ __launch_bounds__(64) void logits_k(const float* __restrict__ pooled, const float* __restrict__ Wc,
                                               const float* __restrict__ bc, float* __restrict__ out, int nc) {
    int g = blockIdx.x;
    int j = threadIdx.x;
    if (j >= nc) return;
    float acc = bc[j];
    const float* p = pooled + (size_t)g * 128;
#pragma unroll 8
    for (int k = 0; k < 128; k++) acc += p[k] * Wc[k * nc + j];
    out[(size_t)g * nc + j] = acc;
}

extern "C" void kernel_launch(void* const* d_in, const int* in_sizes, int n_in,
                              void* d_out, int out_size, void* d_ws, size_t ws_size,
                              hipStream_t stream) {
    const float* x     = (const float*)d_in[0];
    const int*   ei    = (const int*)d_in[1];
    const int*   batch = (const int*)d_in[2];
    const float* W1    = (const float*)d_in[3];
    const float* b1    = (const float*)d_in[4];
    const float* W2    = (const float*)d_in[5];
    const float* b2    = (const float*)d_in[6];
    const float* Wc    = (const float*)d_in[7];
    const float* bc    = (const float*)d_in[8];
    float* out = (float*)d_out;

    const int N = in_sizes[0] / 128;
    const int E = in_sizes[1] / 2;
    const int NC = 10;
    const int G = out_size / (NC + 128);

    const int* src = ei;
    const int* dst = ei + E;

    const int EB   = 16384;
    const int NBLK = (E + EB - 1) / EB;
    const int NBUK = (N + 255) / 256;

    // workspace carve (256B aligned)
    char* wbase = (char*)d_ws;
    size_t off = 0;
    auto alloc = [&](size_t bytes) -> void* {
        void* p = wbase + off;
        off = (off + bytes + 255) & ~(size_t)255;
        return p;
    };
    int*   cnt     = (int*)alloc((size_t)N * 4);
    float* dis     = (float*)alloc((size_t)N * 4);
    int*   row_ptr = (int*)alloc((size_t)(N + 1) * 4);
    int*   hist    = (int*)alloc((size_t)NBUK * NBLK * 4);
    int*   btot    = (int*)alloc((size_t)NBUK * 4);
    int*   bbase   = (int*)alloc((size_t)(NBUK + 1) * 4);
    unsigned int* coarse = (unsigned int*)alloc((size_t)E * 4);
    int*   col     = (int*)alloc((size_t)E * 4);
    unsigned short* bufX = (unsigned short*)alloc((size_t)N * 128 * 2);
    unsigned short* bufT = (unsigned short*)alloc((size_t)N * 128 * 2);
    unsigned short* bufH = (unsigned short*)alloc((size_t)N * 128 * 2);

    // CSR build (no global atomics on big arrays, no memsets needed)
    hist_k<<<NBLK, 256, 0, stream>>>(dst, hist, E, NBUK, NBLK, EB);
    scanA_k<<<(NBUK * 64 + 255) / 256, 256, 0, stream>>>(hist, btot, NBUK, NBLK);
    scanB_k<<<1, 512, 0, stream>>>(btot, bbase, NBUK);
    scatter_k<<<NBLK, 256, 0, stream>>>(src, dst, hist, bbase, coarse, E, NBUK, NBLK, EB);
    bucket_k<<<NBUK, 256, 0, stream>>>(coarse, bbase, cnt, row_ptr, col, N, NBUK, E);
    dis_k<<<(N + 255) / 256, 256, 0, stream>>>(cnt, dis, N);

    cast_bf_k<<<(N * 128 / 4 + 255) / 256, 256, 0, stream>>>(x, bufX, N * 128 / 4);

    gemm_mfma_k<<<512, 256, 0, stream>>>(bufX, W1, dis, bufT, N);
    agg_k<<<(N + 3) / 4, 256, 0, stream>>>(bufT, bufH, row_ptr, col, dis, b1, N);
    gemm_mfma_k<<<512, 256, 0, stream>>>(bufH, W2, dis, bufT, N);
    agg_k<<<(N + 3) / 4, 256, 0, stream>>>(bufT, bufH, row_ptr, col, dis, b2, N);

    float* pooled = out + (size_t)G * NC;
    pool_k<<<G, 128, 0, stream>>>(bufH, batch, pooled, N);
    logits_k<<<G, 64, 0, stream>>>(pooled, Wc, bc, out, NC);
}

// Round 4
// 415.630 us; speedup vs baseline: 2.3226x; 1.0389x over previous
//
#include <hip/hip_runtime.h>
#include <hip/hip_bf16.h>

typedef short bf16x8 __attribute__((ext_vector_type(8)));
typedef float f32x4 __attribute__((ext_vector_type(4)));
typedef unsigned int u32x4 __attribute__((ext_vector_type(4)));

__device__ __forceinline__ unsigned short f2bf(float f) {
    unsigned int u = __float_as_uint(f);
    unsigned int r = u + 0x7fffu + ((u >> 16) & 1u);
    return (unsigned short)(r >> 16);
}
__device__ __forceinline__ float bf2f(unsigned short b) {
    return __uint_as_float(((unsigned int)b) << 16);
}
__device__ __forceinline__ unsigned int packbf2(float lo, float hi) {
    return ((unsigned int)f2bf(hi) << 16) | (unsigned int)f2bf(lo);
}

// ---------------- cast f32 -> bf16 ----------------
__global__ __launch_bounds__(256) void cast_bf_k(const float* __restrict__ x, unsigned short* __restrict__ o, int n4) {
    int i = blockIdx.x * 256 + threadIdx.x;
    if (i < n4) {
        float4 v = ((const float4*)x)[i];
        ushort4 r;
        r.x = f2bf(v.x); r.y = f2bf(v.y); r.z = f2bf(v.z); r.w = f2bf(v.w);
        ((ushort4*)o)[i] = r;
    }
}

// ---------------- pass 1: per-block bucket histogram (bucket = dst>>8) ----------------
__global__ __launch_bounds__(256) void hist_k(const int* __restrict__ dst, int* __restrict__ hist,
                                              int e, int nbuk, int nblk, int eb) {
    __shared__ int lh[512];
    int blk = blockIdx.x, t = threadIdx.x;
    for (int j = t; j < nbuk; j += 256) lh[j] = 0;
    __syncthreads();
    int e0 = blk * eb, e1 = min(e, e0 + eb);
    for (int i = e0 + t; i < e1; i += 256) atomicAdd(&lh[dst[i] >> 8], 1);
    __syncthreads();
    for (int j = t; j < nbuk; j += 256) hist[(size_t)j * nblk + blk] = lh[j];
}

// ---------------- pass 2a: per-bucket exclusive scan over blocks; bucket totals ----------------
__global__ __launch_bounds__(256) void scanA_k(int* __restrict__ hist, int* __restrict__ btot, int nbuk, int nblk) {
    int w = (blockIdx.x * 256 + threadIdx.x) >> 6;
    int lane = threadIdx.x & 63;
    if (w >= nbuk) return;
    size_t base = (size_t)w * nblk;
    int run = 0;
    for (int c = 0; c < nblk; c += 64) {
        int i = c + lane;
        int v = (i < nblk) ? hist[base + i] : 0;
        int orig = v;
        for (int d = 1; d < 64; d <<= 1) { int u = __shfl_up(v, d); if (lane >= d) v += u; }
        if (i < nblk) hist[base + i] = run + v - orig;   // exclusive within bucket
        run += __shfl(v, 63);
    }
    if (lane == 0) btot[w] = run;
}

// ---------------- pass 2b: scan bucket totals -> bucket bases ----------------
__global__ __launch_bounds__(512) void scanB_k(const int* __restrict__ btot, int* __restrict__ bbase, int nbuk) {
    __shared__ int s[512];
    int t = threadIdx.x;
    int v = (t < nbuk) ? btot[t] : 0;
    s[t] = v;
    __syncthreads();
    for (int st = 1; st < 512; st <<= 1) {
        int add = (t >= st) ? s[t - st] : 0;
        __syncthreads();
        s[t] += add;
        __syncthreads();
    }
    if (t < nbuk) bbase[t] = s[t] - v;
    if (t == nbuk - 1) bbase[nbuk] = s[t];
}

// ---------------- pass 3: coarse scatter into bucket regions (packed dstlocal|src) ----------------
__global__ __launch_bounds__(256) void scatter_k(const int* __restrict__ src, const int* __restrict__ dst,
                                                 const int* __restrict__ hist, const int* __restrict__ bbase,
                                                 unsigned int* __restrict__ coarse, int e, int nbuk, int nblk, int eb) {
    __shared__ int cur[512];
    int blk = blockIdx.x, t = threadIdx.x;
    for (int j = t; j < nbuk; j += 256) cur[j] = bbase[j] + hist[(size_t)j * nblk + blk];
    __syncthreads();
    int e0 = blk * eb, e1 = min(e, e0 + eb);
    for (int i = e0 + t; i < e1; i += 256) {
        int s = src[i], d = dst[i];
        int bk = d >> 8;
        int p = atomicAdd(&cur[bk], 1);
        coarse[p] = ((unsigned int)(d & 255) << 24) | (unsigned int)s;
    }
}

// ---------------- pass 4: per-bucket fine sort -> row_ptr, col, dis ----------------
__global__ __launch_bounds__(256) void bucket_k(const unsigned int* __restrict__ coarse, const int* __restrict__ bbase,
                                                float* __restrict__ dis, int* __restrict__ row_ptr, int* __restrict__ col,
                                                int n, int nbuk, int e) {
    __shared__ int h[256];
    __shared__ int s[256];
    __shared__ int cur[256];
    int b = blockIdx.x, t = threadIdx.x;
    int e0 = bbase[b], e1 = bbase[b + 1];
    h[t] = 0;
    __syncthreads();
    for (int i = e0 + t; i < e1; i += 256) atomicAdd(&h[coarse[i] >> 24], 1);
    __syncthreads();
    int v = h[t];
    s[t] = v;
    __syncthreads();
    for (int st = 1; st < 256; st <<= 1) {
        int add = (t >= st) ? s[t - st] : 0;
        __syncthreads();
        s[t] += add;
        __syncthreads();
    }
    int excl = s[t] - v;
    int node = b * 256 + t;
    if (node < n) {
        row_ptr[node] = e0 + excl;
        dis[node] = rsqrtf((float)v + 1.0f);
    }
    cur[t] = e0 + excl;
    __syncthreads();
    for (int i = e0 + t; i < e1; i += 256) {
        unsigned int pk = coarse[i];
        int p = atomicAdd(&cur[pk >> 24], 1);
        col[p] = (int)(pk & 0x00FFFFFFu);
    }
    if (b == nbuk - 1 && t == 0) row_ptr[n] = e;
}

// ---------------- MFMA GEMM: C[r] = dis[r] * (A[r] @ W), A/C bf16, W f32 staged as W^T bf16 ----------------
__global__ __launch_bounds__(256) void gemm_mfma_k(const unsigned short* __restrict__ A, const float* __restrict__ W,
                                                   const float* __restrict__ dis, unsigned short* __restrict__ C,
                                                   int nrows) {
    __shared__ unsigned short WT[128 * 136];   // W^T[n][k], pad ld=136 to dodge bank conflicts
    int t = threadIdx.x;
    for (int i = t; i < 16384; i += 256) {
        int k = i >> 7, nn = i & 127;
        WT[nn * 136 + k] = f2bf(W[i]);
    }
    __syncthreads();
    int wave = t >> 6, lane = t & 63;
    int lm = lane & 15, lg = lane >> 4;      // lg in 0..3
    for (int m0 = blockIdx.x * 64; m0 < nrows; m0 += gridDim.x * 64) {
        int R = m0 + wave * 16;
        int arow = R + lm;
        if (arow >= nrows) arow = nrows - 1;
        const u32x4* ap = (const u32x4*)(A + (size_t)arow * 128);
        f32x4 acc[8];
#pragma unroll
        for (int q = 0; q < 8; q++) acc[q] = (f32x4){0.f, 0.f, 0.f, 0.f};
#pragma unroll
        for (int kk = 0; kk < 4; kk++) {
            bf16x8 af = __builtin_bit_cast(bf16x8, ap[kk * 4 + lg]);   // A[m=lm][k=kk*32+lg*8 ..+7]
#pragma unroll
            for (int q = 0; q < 8; q++) {
                const u32x4* bp = (const u32x4*)(WT + (q * 16 + lm) * 136 + kk * 32 + lg * 8);
                bf16x8 bfr = __builtin_bit_cast(bf16x8, *bp);          // B[k][n=q*16+lm]
                acc[q] = __builtin_amdgcn_mfma_f32_16x16x32_bf16(af, bfr, acc[q], 0, 0, 0);
            }
        }
        float dsc[4];
#pragma unroll
        for (int i2 = 0; i2 < 4; i2++) {
            int r = R + lg * 4 + i2;
            dsc[i2] = (r < nrows) ? dis[r] : 0.f;
        }
#pragma unroll
        for (int i2 = 0; i2 < 4; i2++) {
            int r = R + lg * 4 + i2;
            if (r < nrows) {
                unsigned short* cp = C + (size_t)r * 128 + lm;
#pragma unroll
                for (int q = 0; q < 8; q++) cp[q * 16] = f2bf(acc[q][i2] * dsc[i2]);
            }
        }
    }
}

// ---------------- aggregation: out[n] = relu(b + dis[n]*(h'[n] + sum h'[col[e]]))
// wave = 1 node; 4 edge-streams x 16 lanes; each lane gathers 16 B (8 bf16)
__global__ __launch_bounds__(256) void agg_k(const unsigned short* __restrict__ h, unsigned short* __restrict__ out,
                                             const int* __restrict__ row_ptr, const int* __restrict__ col,
                                             const float* __restrict__ dis, const float* __restrict__ bias, int n) {
    int wid  = (blockIdx.x * 256 + threadIdx.x) >> 6;
    int lane = threadIdx.x & 63;
    if (wid >= n) return;
    int g = lane >> 4;                 // edge stream 0..3
    int s = lane & 15;                 // 16B chunk within 256B row
    const char* hb = (const char*)h;
    unsigned int soff = (unsigned int)(s << 4);
    float acc0 = 0.f, acc1 = 0.f, acc2 = 0.f, acc3 = 0.f;
    float acc4 = 0.f, acc5 = 0.f, acc6 = 0.f, acc7 = 0.f;
#define ACCUM(v)                                                                              \
    acc0 += __uint_as_float((v)[0] << 16); acc1 += __uint_as_float((v)[0] & 0xffff0000u);     \
    acc2 += __uint_as_float((v)[1] << 16); acc3 += __uint_as_float((v)[1] & 0xffff0000u);     \
    acc4 += __uint_as_float((v)[2] << 16); acc5 += __uint_as_float((v)[2] & 0xffff0000u);     \
    acc6 += __uint_as_float((v)[3] << 16); acc7 += __uint_as_float((v)[3] & 0xffff0000u);
    if (g == 0) {   // self-loop row
        u32x4 v = *(const u32x4*)(hb + (((unsigned int)wid << 8) + soff));
        ACCUM(v)
    }
    int e = row_ptr[wid] + g, e1 = row_ptr[wid + 1];
    for (; e + 4 < e1; e += 8) {
        unsigned int o0 = ((unsigned int)col[e] << 8) + soff;
        unsigned int o1 = ((unsigned int)col[e + 4] << 8) + soff;
        u32x4 v0 = *(const u32x4*)(hb + o0);
        u32x4 v1 = *(const u32x4*)(hb + o1);
        ACCUM(v0)
        ACCUM(v1)
    }
    if (e < e1) {
        u32x4 v0 = *(const u32x4*)(hb + (((unsigned int)col[e] << 8) + soff));
        ACCUM(v0)
    }
#undef ACCUM
    // combine the 4 edge-streams (lane bits 4,5)
#define RED(a) a += __shfl_xor(a, 16); a += __shfl_xor(a, 32);
    RED(acc0) RED(acc1) RED(acc2) RED(acc3) RED(acc4) RED(acc5) RED(acc6) RED(acc7)
#undef RED
    if (g == 0) {
        float d = dis[wid];
        const float4* bp = (const float4*)bias;
        float4 ba = bp[2 * s], bb = bp[2 * s + 1];
        u32x4 r;
        r[0] = packbf2(fmaxf(ba.x + d * acc0, 0.f), fmaxf(ba.y + d * acc1, 0.f));
        r[1] = packbf2(fmaxf(ba.z + d * acc2, 0.f), fmaxf(ba.w + d * acc3, 0.f));
        r[2] = packbf2(fmaxf(bb.x + d * acc4, 0.f), fmaxf(bb.y + d * acc5, 0.f));
        r[3] = packbf2(fmaxf(bb.z + d * acc6, 0.f), fmaxf(bb.w + d * acc7, 0.f));
        *(u32x4*)((char*)out + (((unsigned int)wid << 8) + soff)) = r;
    }
}

// ---------------- fused global mean pool + classifier ----------------
__global__ __launch_bounds__(128) void pool_logits_k(const unsigned short* __restrict__ h, const int* __restrict__ batch,
                                                     const float* __restrict__ Wc, const float* __restrict__ bc,
                                                     float* __restrict__ logits, float* __restrict__ pooled,
                                                     int n, int nc) {
    __shared__ float pl[128];
    int g = blockIdx.x;
    int j = threadIdx.x;
    int lo = 0, hi = n;
    while (lo < hi) { int mid = (lo + hi) >> 1; if (batch[mid] < g) lo = mid + 1; else hi = mid; }
    int start = lo;
    hi = n;
    while (lo < hi) { int mid = (lo + hi) >> 1; if (batch[mid] < g + 1) lo = mid + 1; else hi = mid; }
    int end = lo;
    float acc = 0.f;
    for (int r = start; r < end; r++) acc += bf2f(h[(size_t)r * 128 + j]);
    float pv = acc / fmaxf((float)(end - start), 1.0f);
    pooled[(size_t)g * 128 + j] = pv;
    pl[j] = pv;
    __syncthreads();
    if (j < nc) {
        float a = bc[j];
#pragma unroll 8
        for (int k = 0; k < 128; k++) a += pl[k] * Wc[k * nc + j];
        logits[(size_t)g * nc + j] = a;
    }
}

extern "C" void kernel_launch(void* const* d_in, const int* in_sizes, int n_in,
                              void* d_out, int out_size, void* d_ws, size_t ws_size,
                              hipStream_t stream) {
    const float* x     = (const float*)d_in[0];
    const int*   ei    = (const int*)d_in[1];
    const int*   batch = (const int*)d_in[2];
    const float* W1    = (const float*)d_in[3];
    const float* b1    = (const float*)d_in[4];
    const float* W2    = (const float*)d_in[5];
    const float* b2    = (const float*)d_in[6];
    const float* Wc    = (const float*)d_in[7];
    const float* bc    = (const float*)d_in[8];
    float* out = (float*)d_out;

    const int N = in_sizes[0] / 128;
    const int E = in_sizes[1] / 2;
    const int NC = 10;
    const int G = out_size / (NC + 128);

    const int* src = ei;
    const int* dst = ei + E;

    const int EB   = 16384;
    const int NBLK = (E + EB - 1) / EB;
    const int NBUK = (N + 255) / 256;

    // workspace carve (256B aligned)
    char* wbase = (char*)d_ws;
    size_t off = 0;
    auto alloc = [&](size_t bytes) -> void* {
        void* p = wbase + off;
        off = (off + bytes + 255) & ~(size_t)255;
        return p;
    };
    float* dis     = (float*)alloc((size_t)N * 4);
    int*   row_ptr = (int*)alloc((size_t)(N + 1) * 4);
    int*   hist    = (int*)alloc((size_t)NBUK * NBLK * 4);
    int*   btot    = (int*)alloc((size_t)NBUK * 4);
    int*   bbase   = (int*)alloc((size_t)(NBUK + 1) * 4);
    unsigned int* coarse = (unsigned int*)alloc((size_t)E * 4);
    int*   col     = (int*)alloc((size_t)E * 4);
    unsigned short* bufX = (unsigned short*)alloc((size_t)N * 128 * 2);
    unsigned short* bufT = (unsigned short*)alloc((size_t)N * 128 * 2);
    unsigned short* bufH = (unsigned short*)alloc((size_t)N * 128 * 2);

    // CSR build (no big global atomics, no memsets)
    hist_k<<<NBLK, 256, 0, stream>>>(dst, hist, E, NBUK, NBLK, EB);
    scanA_k<<<(NBUK * 64 + 255) / 256, 256, 0, stream>>>(hist, btot, NBUK, NBLK);
    scanB_k<<<1, 512, 0, stream>>>(btot, bbase, NBUK);
    scatter_k<<<NBLK, 256, 0, stream>>>(src, dst, hist, bbase, coarse, E, NBUK, NBLK, EB);
    bucket_k<<<NBUK, 256, 0, stream>>>(coarse, bbase, dis, row_ptr, col, N, NBUK, E);

    cast_bf_k<<<(N * 128 / 4 + 255) / 256, 256, 0, stream>>>(x, bufX, N * 128 / 4);

    gemm_mfma_k<<<512, 256, 0, stream>>>(bufX, W1, dis, bufT, N);
    agg_k<<<(N + 3) / 4, 256, 0, stream>>>(bufT, bufH, row_ptr, col, dis, b1, N);
    gemm_mfma_k<<<512, 256, 0, stream>>>(bufH, W2, dis, bufT, N);
    agg_k<<<(N + 3) / 4, 256, 0, stream>>>(bufT, bufH, row_ptr, col, dis, b2, N);

    float* pooled = out + (size_t)G * NC;
    pool_logits_k<<<G, 128, 0, stream>>>(bufH, batch, Wc, bc, out, pooled, N, NC);
}

// Round 5
// 401.446 us; speedup vs baseline: 2.4047x; 1.0353x over previous
//
#include <hip/hip_runtime.h>
#include <hip/hip_bf16.h>

typedef short bf16x8 __attribute__((ext_vector_type(8)));
typedef float f32x4 __attribute__((ext_vector_type(4)));
typedef unsigned int u32x4 __attribute__((ext_vector_type(4)));

__device__ __forceinline__ unsigned short f2bf(float f) {
    unsigned int u = __float_as_uint(f);
    unsigned int r = u + 0x7fffu + ((u >> 16) & 1u);
    return (unsigned short)(r >> 16);
}
__device__ __forceinline__ float bf2f(unsigned short b) {
    return __uint_as_float(((unsigned int)b) << 16);
}
__device__ __forceinline__ unsigned int packbf2(float lo, float hi) {
    return ((unsigned int)f2bf(hi) << 16) | (unsigned int)f2bf(lo);
}

// ---------------- pass 1: per-block bucket histogram (bucket = dst>>8) ----------------
__global__ __launch_bounds__(256) void hist_k(const int* __restrict__ dst, int* __restrict__ hist,
                                              int e, int nbuk, int nblk, int eb) {
    __shared__ int lh[512];
    int blk = blockIdx.x, t = threadIdx.x;
    for (int j = t; j < nbuk; j += 256) lh[j] = 0;
    __syncthreads();
    int e0 = blk * eb, e1 = min(e, e0 + eb);
    for (int i = e0 + t; i < e1; i += 256) atomicAdd(&lh[dst[i] >> 8], 1);
    __syncthreads();
    for (int j = t; j < nbuk; j += 256) hist[(size_t)j * nblk + blk] = lh[j];
}

// ---------------- pass 2a: per-bucket exclusive scan over blocks; bucket totals ----------------
__global__ __launch_bounds__(256) void scanA_k(int* __restrict__ hist, int* __restrict__ btot, int nbuk, int nblk) {
    int w = (blockIdx.x * 256 + threadIdx.x) >> 6;
    int lane = threadIdx.x & 63;
    if (w >= nbuk) return;
    size_t base = (size_t)w * nblk;
    int run = 0;
    for (int c = 0; c < nblk; c += 64) {
        int i = c + lane;
        int v = (i < nblk) ? hist[base + i] : 0;
        int orig = v;
        for (int d = 1; d < 64; d <<= 1) { int u = __shfl_up(v, d); if (lane >= d) v += u; }
        if (i < nblk) hist[base + i] = run + v - orig;   // exclusive within bucket
        run += __shfl(v, 63);
    }
    if (lane == 0) btot[w] = run;
}

// ---------------- pass 2b: scan bucket totals -> bucket bases ----------------
__global__ __launch_bounds__(512) void scanB_k(const int* __restrict__ btot, int* __restrict__ bbase, int nbuk) {
    __shared__ int s[512];
    int t = threadIdx.x;
    int v = (t < nbuk) ? btot[t] : 0;
    s[t] = v;
    __syncthreads();
    for (int st = 1; st < 512; st <<= 1) {
        int add = (t >= st) ? s[t - st] : 0;
        __syncthreads();
        s[t] += add;
        __syncthreads();
    }
    if (t < nbuk) bbase[t] = s[t] - v;
    if (t == nbuk - 1) bbase[nbuk] = s[t];
}

// ---------------- pass 3: coarse scatter into bucket regions (packed dstlocal|src) ----------------
__global__ __launch_bounds__(256) void scatter_k(const int* __restrict__ src, const int* __restrict__ dst,
                                                 const int* __restrict__ hist, const int* __restrict__ bbase,
                                                 unsigned int* __restrict__ coarse, int e, int nbuk, int nblk, int eb) {
    __shared__ int cur[512];
    int blk = blockIdx.x, t = threadIdx.x;
    for (int j = t; j < nbuk; j += 256) cur[j] = bbase[j] + hist[(size_t)j * nblk + blk];
    __syncthreads();
    int e0 = blk * eb, e1 = min(e, e0 + eb);
    for (int i = e0 + t; i < e1; i += 256) {
        int s = src[i], d = dst[i];
        int bk = d >> 8;
        int p = atomicAdd(&cur[bk], 1);
        coarse[p] = ((unsigned int)(d & 255) << 24) | (unsigned int)s;
    }
}

// ---------------- pass 4: per-bucket fine sort -> row_ptr, col, dis ----------------
__global__ __launch_bounds__(256) void bucket_k(const unsigned int* __restrict__ coarse, const int* __restrict__ bbase,
                                                float* __restrict__ dis, int* __restrict__ row_ptr, int* __restrict__ col,
                                                int n, int nbuk, int e) {
    __shared__ int h[256];
    __shared__ int s[256];
    __shared__ int cur[256];
    int b = blockIdx.x, t = threadIdx.x;
    int e0 = bbase[b], e1 = bbase[b + 1];
    h[t] = 0;
    __syncthreads();
    for (int i = e0 + t; i < e1; i += 256) atomicAdd(&h[coarse[i] >> 24], 1);
    __syncthreads();
    int v = h[t];
    s[t] = v;
    __syncthreads();
    for (int st = 1; st < 256; st <<= 1) {
        int add = (t >= st) ? s[t - st] : 0;
        __syncthreads();
        s[t] += add;
        __syncthreads();
    }
    int excl = s[t] - v;
    int node = b * 256 + t;
    if (node < n) {
        row_ptr[node] = e0 + excl;
        dis[node] = rsqrtf((float)v + 1.0f);
    }
    cur[t] = e0 + excl;
    __syncthreads();
    for (int i = e0 + t; i < e1; i += 256) {
        unsigned int pk = coarse[i];
        int p = atomicAdd(&cur[pk >> 24], 1);
        col[p] = (int)(pk & 0x00FFFFFFu);
    }
    if (b == nbuk - 1 && t == 0) row_ptr[n] = e;
}

// ---------------- MFMA GEMM: C[r] = dis[r] * (A[r] @ W); A f32 (layer1) or bf16; C bf16 ----------------
template <bool INF32>
__global__ __launch_bounds__(256) void gemm_mfma_k(const void* __restrict__ Av, const float* __restrict__ W,
                                                   const float* __restrict__ dis, unsigned short* __restrict__ C,
                                                   int nrows) {
    __shared__ unsigned short WT[128 * 136];   // W^T[n][k], pad ld=136 to dodge bank conflicts
    int t = threadIdx.x;
    for (int i = t; i < 16384; i += 256) {
        int k = i >> 7, nn = i & 127;
        WT[nn * 136 + k] = f2bf(W[i]);
    }
    __syncthreads();
    int wave = t >> 6, lane = t & 63;
    int lm = lane & 15, lg = lane >> 4;      // lg in 0..3
    for (int m0 = blockIdx.x * 64; m0 < nrows; m0 += gridDim.x * 64) {
        int R = m0 + wave * 16;
        int arow = R + lm;
        if (arow >= nrows) arow = nrows - 1;
        f32x4 acc[8];
#pragma unroll
        for (int q = 0; q < 8; q++) acc[q] = (f32x4){0.f, 0.f, 0.f, 0.f};
#pragma unroll
        for (int kk = 0; kk < 4; kk++) {
            bf16x8 af;
            if constexpr (INF32) {
                const float4* ap = (const float4*)((const float*)Av + (size_t)arow * 128 + kk * 32 + lg * 8);
                float4 a0 = ap[0], a1 = ap[1];
                u32x4 au;
                au[0] = packbf2(a0.x, a0.y); au[1] = packbf2(a0.z, a0.w);
                au[2] = packbf2(a1.x, a1.y); au[3] = packbf2(a1.z, a1.w);
                af = __builtin_bit_cast(bf16x8, au);
            } else {
                const u32x4* ap = (const u32x4*)((const unsigned short*)Av + (size_t)arow * 128);
                af = __builtin_bit_cast(bf16x8, ap[kk * 4 + lg]);
            }
#pragma unroll
            for (int q = 0; q < 8; q++) {
                const u32x4* bp = (const u32x4*)(WT + (q * 16 + lm) * 136 + kk * 32 + lg * 8);
                bf16x8 bfr = __builtin_bit_cast(bf16x8, *bp);          // B[k][n=q*16+lm]
                acc[q] = __builtin_amdgcn_mfma_f32_16x16x32_bf16(af, bfr, acc[q], 0, 0, 0);
            }
        }
        float dsc[4];
#pragma unroll
        for (int i2 = 0; i2 < 4; i2++) {
            int r = R + lg * 4 + i2;
            dsc[i2] = (r < nrows) ? dis[r] : 0.f;
        }
#pragma unroll
        for (int i2 = 0; i2 < 4; i2++) {
            int r = R + lg * 4 + i2;
            if (r < nrows) {
                unsigned short* cp = C + (size_t)r * 128 + lm;
#pragma unroll
                for (int q = 0; q < 8; q++) cp[q * 16] = f2bf(acc[q][i2] * dsc[i2]);
            }
        }
    }
}

// ---------------- aggregation: out[n] = relu(b + dis[n]*(h'[n] + sum h'[col[e]]))
// wave = 1 node; 4 edge-streams x 16 lanes; each lane gathers 16 B; 4-deep unroll per stream
__global__ __launch_bounds__(256) void agg_k(const unsigned short* __restrict__ h, unsigned short* __restrict__ out,
                                             const int* __restrict__ row_ptr, const int* __restrict__ col,
                                             const float* __restrict__ dis, const float* __restrict__ bias, int n) {
    int wid  = (blockIdx.x * 256 + threadIdx.x) >> 6;
    int lane = threadIdx.x & 63;
    if (wid >= n) return;
    int g = lane >> 4;                 // edge stream 0..3
    int s = lane & 15;                 // 16B chunk within 256B row
    const char* hb = (const char*)h;
    unsigned int soff = (unsigned int)(s << 4);
    float acc0 = 0.f, acc1 = 0.f, acc2 = 0.f, acc3 = 0.f;
    float acc4 = 0.f, acc5 = 0.f, acc6 = 0.f, acc7 = 0.f;
#define ACCUM(v)                                                                              \
    acc0 += __uint_as_float((v)[0] << 16); acc1 += __uint_as_float((v)[0] & 0xffff0000u);     \
    acc2 += __uint_as_float((v)[1] << 16); acc3 += __uint_as_float((v)[1] & 0xffff0000u);     \
    acc4 += __uint_as_float((v)[2] << 16); acc5 += __uint_as_float((v)[2] & 0xffff0000u);     \
    acc6 += __uint_as_float((v)[3] << 16); acc7 += __uint_as_float((v)[3] & 0xffff0000u);
    if (g == 0) {   // self-loop row
        u32x4 v = *(const u32x4*)(hb + (((unsigned int)wid << 8) + soff));
        ACCUM(v)
    }
    int e = row_ptr[wid] + g, e1 = row_ptr[wid + 1];
    // main loop: 4 edges per stream in flight (16 rows / 4 KB per wave)
    for (; e + 12 < e1; e += 16) {
        int c0 = col[e], c1 = col[e + 4], c2 = col[e + 8], c3 = col[e + 12];
        u32x4 v0 = *(const u32x4*)(hb + (((unsigned int)c0 << 8) + soff));
        u32x4 v1 = *(const u32x4*)(hb + (((unsigned int)c1 << 8) + soff));
        u32x4 v2 = *(const u32x4*)(hb + (((unsigned int)c2 << 8) + soff));
        u32x4 v3 = *(const u32x4*)(hb + (((unsigned int)c3 << 8) + soff));
        ACCUM(v0)
        ACCUM(v1)
        ACCUM(v2)
        ACCUM(v3)
    }
    for (; e < e1; e += 4) {
        u32x4 v = *(const u32x4*)(hb + (((unsigned int)col[e] << 8) + soff));
        ACCUM(v)
    }
#undef ACCUM
    // combine the 4 edge-streams (lane bits 4,5)
#define RED(a) a += __shfl_xor(a, 16); a += __shfl_xor(a, 32);
    RED(acc0) RED(acc1) RED(acc2) RED(acc3) RED(acc4) RED(acc5) RED(acc6) RED(acc7)
#undef RED
    if (g == 0) {
        float d = dis[wid];
        const float4* bp = (const float4*)bias;
        float4 ba = bp[2 * s], bb = bp[2 * s + 1];
        u32x4 r;
        r[0] = packbf2(fmaxf(ba.x + d * acc0, 0.f), fmaxf(ba.y + d * acc1, 0.f));
        r[1] = packbf2(fmaxf(ba.z + d * acc2, 0.f), fmaxf(ba.w + d * acc3, 0.f));
        r[2] = packbf2(fmaxf(bb.x + d * acc4, 0.f), fmaxf(bb.y + d * acc5, 0.f));
        r[3] = packbf2(fmaxf(bb.z + d * acc6, 0.f), fmaxf(bb.w + d * acc7, 0.f));
        *(u32x4*)((char*)out + (((unsigned int)wid << 8) + soff)) = r;
    }
}

// ---------------- fused global mean pool + classifier ----------------
__global__ __launch_bounds__(128) void pool_logits_k(const unsigned short* __restrict__ h, const int* __restrict__ batch,
                                                     const float* __restrict__ Wc, const float* __restrict__ bc,
                                                     float* __restrict__ logits, float* __restrict__ pooled,
                                                     int n, int nc) {
    __shared__ float pl[128];
    int g = blockIdx.x;
    int j = threadIdx.x;
    int lo = 0, hi = n;
    while (lo < hi) { int mid = (lo + hi) >> 1; if (batch[mid] < g) lo = mid + 1; else hi = mid; }
    int start = lo;
    hi = n;
    while (lo < hi) { int mid = (lo + hi) >> 1; if (batch[mid] < g + 1) lo = mid + 1; else hi = mid; }
    int end = lo;
    float acc = 0.f;
    for (int r = start; r < end; r++) acc += bf2f(h[(size_t)r * 128 + j]);
    float pv = acc / fmaxf((float)(end - start), 1.0f);
    pooled[(size_t)g * 128 + j] = pv;
    pl[j] = pv;
    __syncthreads();
    if (j < nc) {
        float a = bc[j];
#pragma unroll 8
        for (int k = 0; k < 128; k++) a += pl[k] * Wc[k * nc + j];
        logits[(size_t)g * nc + j] = a;
    }
}

extern "C" void kernel_launch(void* const* d_in, const int* in_sizes, int n_in,
                              void* d_out, int out_size, void* d_ws, size_t ws_size,
                              hipStream_t stream) {
    const float* x     = (const float*)d_in[0];
    const int*   ei    = (const int*)d_in[1];
    const int*   batch = (const int*)d_in[2];
    const float* W1    = (const float*)d_in[3];
    const float* b1    = (const float*)d_in[4];
    const float* W2    = (const float*)d_in[5];
    const float* b2    = (const float*)d_in[6];
    const float* Wc    = (const float*)d_in[7];
    const float* bc    = (const float*)d_in[8];
    float* out = (float*)d_out;

    const int N = in_sizes[0] / 128;
    const int E = in_sizes[1] / 2;
    const int NC = 10;
    const int G = out_size / (NC + 128);

    const int* src = ei;
    const int* dst = ei + E;

    const int EB   = 16384;
    const int NBLK = (E + EB - 1) / EB;
    const int NBUK = (N + 255) / 256;

    // workspace carve (256B aligned)
    char* wbase = (char*)d_ws;
    size_t off = 0;
    auto alloc = [&](size_t bytes) -> void* {
        void* p = wbase + off;
        off = (off + bytes + 255) & ~(size_t)255;
        return p;
    };
    float* dis     = (float*)alloc((size_t)N * 4);
    int*   row_ptr = (int*)alloc((size_t)(N + 1) * 4);
    int*   hist    = (int*)alloc((size_t)NBUK * NBLK * 4);
    int*   btot    = (int*)alloc((size_t)NBUK * 4);
    int*   bbase   = (int*)alloc((size_t)(NBUK + 1) * 4);
    unsigned int* coarse = (unsigned int*)alloc((size_t)E * 4);
    int*   col     = (int*)alloc((size_t)E * 4);
    unsigned short* bufT = (unsigned short*)alloc((size_t)N * 128 * 2);
    unsigned short* bufH = (unsigned short*)alloc((size_t)N * 128 * 2);

    // CSR build (no big global atomics, no memsets)
    hist_k<<<NBLK, 256, 0, stream>>>(dst, hist, E, NBUK, NBLK, EB);
    scanA_k<<<(NBUK * 64 + 255) / 256, 256, 0, stream>>>(hist, btot, NBUK, NBLK);
    scanB_k<<<1, 512, 0, stream>>>(btot, bbase, NBUK);
    scatter_k<<<NBLK, 256, 0, stream>>>(src, dst, hist, bbase, coarse, E, NBUK, NBLK, EB);
    bucket_k<<<NBUK, 256, 0, stream>>>(coarse, bbase, dis, row_ptr, col, N, NBUK, E);

    gemm_mfma_k<true><<<512, 256, 0, stream>>>(x, W1, dis, bufT, N);
    agg_k<<<(N + 3) / 4, 256, 0, stream>>>(bufT, bufH, row_ptr, col, dis, b1, N);
    gemm_mfma_k<false><<<512, 256, 0, stream>>>(bufH, W2, dis, bufT, N);
    agg_k<<<(N + 3) / 4, 256, 0, stream>>>(bufT, bufH, row_ptr, col, dis, b2, N);

    float* pooled = out + (size_t)G * NC;
    pool_logits_k<<<G, 128, 0, stream>>>(bufH, batch, Wc, bc, out, pooled, N, NC);
}